// Round 7
// baseline (381.087 us; speedup 1.0000x reference)
//
#include <hip/hip_runtime.h>

#define NM 2048
#define EM 32768
#define NP 8192
#define EP 262144

typedef __attribute__((ext_vector_type(8))) short short8;
typedef __attribute__((ext_vector_type(4))) short short4v;
typedef __attribute__((ext_vector_type(4))) float f32x4;

#define LOG2E 1.44269504088896340736f

__device__ __forceinline__ float e2(float x) { return __builtin_amdgcn_exp2f(x); }
// pack two fp32 -> bf16x2 by TRUNCATION (1 inst); P in [0,1], ~0.4% worst-case, fine for budget
__device__ __forceinline__ unsigned int pk_bf16_tr(float a, float b) {
    return __builtin_amdgcn_perm(__float_as_uint(a), __float_as_uint(b), 0x03020706u);
}
__device__ __forceinline__ unsigned short cvt_bf16(float f) {
    unsigned int u = __float_as_uint(f);
    u = (u + 0x7fff + ((u >> 16) & 1)) >> 16;   // RNE
    return (unsigned short)u;
}

// ---------------- phase 1: histogram of dst (both graphs) ----------------
__global__ __launch_bounds__(256) void hist_kernel(
    const int* __restrict__ ei_m, const int* __restrict__ ei_p,
    int* __restrict__ cnt_m, int* __restrict__ cnt_p)
{
    int idx = blockIdx.x * 256 + threadIdx.x;
    if (idx < EM) atomicAdd(&cnt_m[ei_m[EM + idx]], 1);
    int j = idx - EM;
    if (j >= 0 && j < EP) atomicAdd(&cnt_p[ei_p[EP + j]], 1);
}

// ---------------- phase 2: exclusive prefix sum (block 0 = mol, block 1 = prot) ----------------
__global__ __launch_bounds__(256) void scan_kernel(
    const int* __restrict__ cnt_m, const int* __restrict__ cnt_p,
    int* __restrict__ start_m, int* __restrict__ start_p,
    int* __restrict__ cur_m, int* __restrict__ cur_p)
{
    const int* cnt; int* start; int* cur; int n;
    if (blockIdx.x == 0) { cnt = cnt_m; start = start_m; cur = cur_m; n = NM; }
    else                 { cnt = cnt_p; start = start_p; cur = cur_p; n = NP; }
    int per = n >> 8;
    int tid = threadIdx.x;
    int base = tid * per;
    int s = 0;
    for (int i = 0; i < per; i++) s += cnt[base + i];
    __shared__ int wsum[4];
    int lane = tid & 63, w = tid >> 6;
    int v = s;
    #pragma unroll
    for (int off = 1; off < 64; off <<= 1) {
        int u = __shfl_up(v, off, 64);
        if (lane >= off) v += u;
    }
    if (lane == 63) wsum[w] = v;
    __syncthreads();
    int wo = 0;
    for (int i = 0; i < w; i++) wo += wsum[i];
    int run = wo + v - s;   // exclusive prefix for this thread's range
    for (int i = 0; i < per; i++) {
        start[base + i] = run; cur[base + i] = run;
        run += cnt[base + i];
    }
    if (tid == 255) start[n] = run;
}

// ------- phase 3: scatter packed (edge<<sh)|src into dst-sorted order -------
__global__ __launch_bounds__(256) void scatter_kernel(
    const int* __restrict__ ei_m, const int* __restrict__ ei_p,
    int* __restrict__ cur_m, int* __restrict__ cur_p,
    int* __restrict__ pidx_m, int* __restrict__ pidx_p)
{
    int idx = blockIdx.x * 256 + threadIdx.x;
    if (idx < EM) {
        int d = ei_m[EM + idx];
        int pos = atomicAdd(&cur_m[d], 1);
        pidx_m[pos] = (idx << 11) | ei_m[idx];          // NM=2048 -> 11 src bits
    }
    int j = idx - EM;
    if (j >= 0 && j < EP) {
        int d = ei_p[EP + j];
        int pos = atomicAdd(&cur_p[d], 1);
        pidx_p[pos] = (j << 13) | ei_p[j];              // NP=8192 -> 13 src bits
    }
}

// ------- phase 4: atomic-free segmented reduce; h0 = x + mean(relu(x[src]+ea)) -------
// wave-uniform index fetch via readfirstlane -> scalar loads (r4 form: best measured)
__global__ __launch_bounds__(256) void node_aggr_kernel(
    const float* __restrict__ x_m, const float* __restrict__ ea_m,
    const int* __restrict__ start_m, const int* __restrict__ pidx_m,
    const float* __restrict__ x_p, const float* __restrict__ ea_p,
    const int* __restrict__ start_p, const int* __restrict__ pidx_p,
    float* __restrict__ h0_m, float* __restrict__ h0_p)
{
    int wave = threadIdx.x >> 6, lane = threadIdx.x & 63;
    int nid = blockIdx.x * 4 + wave;
    const float *x, *ea; const int *start, *pidx; float* h0; int n, sh, msk;
    if (nid < NM) { x = x_m; ea = ea_m; start = start_m; pidx = pidx_m; h0 = h0_m; n = nid; sh = 11; msk = 2047; }
    else          { x = x_p; ea = ea_p; start = start_p; pidx = pidx_p; h0 = h0_p; n = nid - NM; sh = 13; msk = 8191; }
    int b  = __builtin_amdgcn_readfirstlane(start[n]);
    int e  = __builtin_amdgcn_readfirstlane(start[n + 1]);
    int deg = e - b;
    const int* pp = pidx + b;
    float acc = 0.f;
    int j = 0;
    for (; j + 8 <= deg; j += 8) {
        int v0 = __builtin_amdgcn_readfirstlane(pp[j]);
        int v1 = __builtin_amdgcn_readfirstlane(pp[j + 1]);
        int v2 = __builtin_amdgcn_readfirstlane(pp[j + 2]);
        int v3 = __builtin_amdgcn_readfirstlane(pp[j + 3]);
        int v4 = __builtin_amdgcn_readfirstlane(pp[j + 4]);
        int v5 = __builtin_amdgcn_readfirstlane(pp[j + 5]);
        int v6 = __builtin_amdgcn_readfirstlane(pp[j + 6]);
        int v7 = __builtin_amdgcn_readfirstlane(pp[j + 7]);
        float a0 = ea[(size_t)(((unsigned)v0) >> sh) * 64 + lane];
        float a1 = ea[(size_t)(((unsigned)v1) >> sh) * 64 + lane];
        float a2 = ea[(size_t)(((unsigned)v2) >> sh) * 64 + lane];
        float a3 = ea[(size_t)(((unsigned)v3) >> sh) * 64 + lane];
        float a4 = ea[(size_t)(((unsigned)v4) >> sh) * 64 + lane];
        float a5 = ea[(size_t)(((unsigned)v5) >> sh) * 64 + lane];
        float a6 = ea[(size_t)(((unsigned)v6) >> sh) * 64 + lane];
        float a7 = ea[(size_t)(((unsigned)v7) >> sh) * 64 + lane];
        float y0 = x[(size_t)(v0 & msk) * 64 + lane];
        float y1 = x[(size_t)(v1 & msk) * 64 + lane];
        float y2 = x[(size_t)(v2 & msk) * 64 + lane];
        float y3 = x[(size_t)(v3 & msk) * 64 + lane];
        float y4 = x[(size_t)(v4 & msk) * 64 + lane];
        float y5 = x[(size_t)(v5 & msk) * 64 + lane];
        float y6 = x[(size_t)(v6 & msk) * 64 + lane];
        float y7 = x[(size_t)(v7 & msk) * 64 + lane];
        acc += fmaxf(y0 + a0, 0.f); acc += fmaxf(y1 + a1, 0.f);
        acc += fmaxf(y2 + a2, 0.f); acc += fmaxf(y3 + a3, 0.f);
        acc += fmaxf(y4 + a4, 0.f); acc += fmaxf(y5 + a5, 0.f);
        acc += fmaxf(y6 + a6, 0.f); acc += fmaxf(y7 + a7, 0.f);
    }
    for (; j < deg; ++j) {
        int v0 = __builtin_amdgcn_readfirstlane(pp[j]);
        acc += fmaxf(x[(size_t)(v0 & msk) * 64 + lane] + ea[(size_t)(((unsigned)v0) >> sh) * 64 + lane], 0.f);
    }
    float aggr = acc / fmaxf((float)deg, 1.f);
    h0[(size_t)n * 64 + lane] = x[(size_t)n * 64 + lane] + aggr;
}

// ---------------- GINE MLP (both graphs): h = relu( relu(h0@w1+b1)@w2 + b2 ) ----------------
__global__ __launch_bounds__(256) void gine_mlp_kernel(
    const float* __restrict__ h0_m, const float* __restrict__ h0_p,
    const float* __restrict__ w1m, const float* __restrict__ b1m,
    const float* __restrict__ w2m, const float* __restrict__ b2m,
    const float* __restrict__ w1p, const float* __restrict__ b1p,
    const float* __restrict__ w2p, const float* __restrict__ b2p,
    float* __restrict__ hm, float* __restrict__ hp)
{
    const float *h0, *w1, *b1, *w2, *b2; float* out; int row0;
    if (blockIdx.x < NM / 16) {
        h0 = h0_m; w1 = w1m; b1 = b1m; w2 = w2m; b2 = b2m; out = hm;
        row0 = blockIdx.x * 16;
    } else {
        h0 = h0_p; w1 = w1p; b1 = b1p; w2 = w2p; b2 = b2p; out = hp;
        row0 = (blockIdx.x - NM / 16) * 16;
    }
    __shared__ float sW1[4096], sW2[4096], sb1[64], sb2[64];
    __shared__ float sh0[16][64], sh1[16][64];
    int t = threadIdx.x;
    for (int i = t; i < 4096; i += 256) { sW1[i] = w1[i]; sW2[i] = w2[i]; }
    if (t < 64) { sb1[t] = b1[t]; sb2[t] = b2[t]; }
    for (int i = t; i < 16 * 64; i += 256) {
        int r = i >> 6, c = i & 63;
        sh0[r][c] = h0[(size_t)(row0 + r) * 64 + c];
    }
    __syncthreads();
    int j = t & 63, rs = t >> 6;
    for (int r = rs; r < 16; r += 4) {
        float a = sb1[j];
        #pragma unroll
        for (int c = 0; c < 64; c++) a += sh0[r][c] * sW1[c * 64 + j];
        sh1[r][j] = fmaxf(a, 0.0f);
    }
    __syncthreads();
    for (int r = rs; r < 16; r += 4) {
        float a = sb2[j];
        #pragma unroll
        for (int c = 0; c < 64; c++) a += sh1[r][c] * sW2[c * 64 + j];
        out[(size_t)(row0 + r) * 64 + j] = fmaxf(a, 0.0f);   // outer relu fused
    }
}

// -------- fused QKV -> bf16 (both sources) + per-direction Q/K max row-norms --------
// Q pre-scaled by 0.25*log2e. norms[4] (int bits of float): 0=Qm,1=Km,2=Qp,3=Kp
__global__ __launch_bounds__(256) void qkv_bf16_kernel(
    const float* __restrict__ hm, const float* __restrict__ hp,
    const float* __restrict__ wq_m, const float* __restrict__ bq_m,
    const float* __restrict__ wk_m, const float* __restrict__ bk_m,
    const float* __restrict__ wv_m, const float* __restrict__ bv_m,
    const float* __restrict__ wq_p, const float* __restrict__ bq_p,
    const float* __restrict__ wk_p, const float* __restrict__ bk_p,
    const float* __restrict__ wv_p, const float* __restrict__ bv_p,
    unsigned short* __restrict__ Qm, unsigned short* __restrict__ Km, unsigned short* __restrict__ Vtm,
    unsigned short* __restrict__ Qp, unsigned short* __restrict__ Kp, unsigned short* __restrict__ Vtp,
    int* __restrict__ norms)
{
    const float *x, *wq, *bq, *wk, *bk, *wv, *bv;
    unsigned short *Q, *K, *Vt; int row0, N, nbase;
    if (blockIdx.x < NM / 16) {
        x = hm; wq = wq_m; bq = bq_m; wk = wk_m; bk = bk_m; wv = wv_m; bv = bv_m;
        Q = Qm; K = Km; Vt = Vtm; N = NM; row0 = blockIdx.x * 16; nbase = 0;
    } else {
        x = hp; wq = wq_p; bq = bq_p; wk = wk_p; bk = bk_p; wv = wv_p; bv = bv_p;
        Q = Qp; K = Kp; Vt = Vtp; N = NP; row0 = (blockIdx.x - NM / 16) * 16; nbase = 2;
    }
    __shared__ float sWq[4096], sWk[4096], sWv[4096];
    __shared__ float sbq[64], sbk[64], sbv[64];
    __shared__ float sh0[16][64];
    __shared__ float rmx[8];
    int t = threadIdx.x;
    for (int i = t; i < 4096; i += 256) { sWq[i] = wq[i]; sWk[i] = wk[i]; sWv[i] = wv[i]; }
    if (t < 64) { sbq[t] = bq[t]; sbk[t] = bk[t]; sbv[t] = bv[t]; }
    for (int i = t; i < 16 * 64; i += 256) {
        int r = i >> 6, c = i & 63;
        sh0[r][c] = x[(size_t)(row0 + r) * 64 + c];
    }
    __syncthreads();
    int j = t & 63, rs = t >> 6;
    float qmx = 0.f, kmx = 0.f;
    for (int r = rs; r < 16; r += 4) {
        float aq = sbq[j], ak = sbk[j], av = sbv[j];
        #pragma unroll
        for (int c = 0; c < 64; c++) {
            float h = sh0[r][c];
            aq += h * sWq[c * 64 + j];
            ak += h * sWk[c * 64 + j];
            av += h * sWv[c * 64 + j];
        }
        float qs = aq * (0.25f * LOG2E);      // fold 1/sqrt(HD) and log2(e)
        size_t o = (size_t)(row0 + r) * 64 + j;
        Q[o] = cvt_bf16(qs);
        K[o] = cvt_bf16(ak);
        Vt[(size_t)j * N + row0 + r] = cvt_bf16(av);
        // per-(row,head) sum of squares over the 16-lane head group
        float qsq = qs * qs, ksq = ak * ak;
        #pragma unroll
        for (int o2 = 1; o2 <= 8; o2 <<= 1) {
            qsq += __shfl_xor(qsq, o2, 64);
            ksq += __shfl_xor(ksq, o2, 64);
        }
        qmx = fmaxf(qmx, qsq);
        kmx = fmaxf(kmx, ksq);
    }
    qmx = fmaxf(qmx, __shfl_xor(qmx, 16, 64)); qmx = fmaxf(qmx, __shfl_xor(qmx, 32, 64));
    kmx = fmaxf(kmx, __shfl_xor(kmx, 16, 64)); kmx = fmaxf(kmx, __shfl_xor(kmx, 32, 64));
    if (j == 0) { rmx[rs] = qmx; rmx[4 + rs] = kmx; }
    __syncthreads();
    if (t == 0) {
        float q4 = fmaxf(fmaxf(rmx[0], rmx[1]), fmaxf(rmx[2], rmx[3]));
        float k4 = fmaxf(fmaxf(rmx[4], rmx[5]), fmaxf(rmx[6], rmx[7]));
        atomicMax(&norms[nbase],     __float_as_int(sqrtf(q4)));
        atomicMax(&norms[nbase + 1], __float_as_int(sqrtf(k4)));
    }
}

// ---------------- LDS-free MFMA flash-attention with fixed upper-bound m ----------------
// P stays in registers: PV's V fragment is loaded with keys PERMUTED to match the QK C-layout
// key order (contraction over k is order-agnostic). No LDS, no transform, no RAW stall.
__global__ __launch_bounds__(256) void attn_kernel(
    const unsigned short* __restrict__ Qm, const unsigned short* __restrict__ Km,
    const unsigned short* __restrict__ Vtm,
    const unsigned short* __restrict__ Qp, const unsigned short* __restrict__ Kp,
    const unsigned short* __restrict__ Vtp,
    const int* __restrict__ norms, float* __restrict__ partial)
{
    int t = threadIdx.x;
    int lane = t & 63;
    int qrow = lane & 15;
    int quad = lane >> 4;
    int T = blockIdx.x * 4 + (t >> 6);

    const unsigned short *Q, *K, *Vt; int Nk, ncb, tloc; float m;
    if (T < 4096) { Q = Qm; K = Kp; Vt = Vtp; Nk = NP; ncb = 3; tloc = T;
                    m = __int_as_float(norms[0]) * __int_as_float(norms[3]); }
    else          { Q = Qp; K = Km; Vt = Vtm; Nk = NM; ncb = 1; tloc = T - 4096;
                    m = __int_as_float(norms[2]) * __int_as_float(norms[1]); }
    int chunk = tloc & ((1 << ncb) - 1);
    int tmp = tloc >> ncb;
    int h = tmp & 3;
    int qt = tmp >> 2;

    // B operand of QK: zero upper K half (k>=16) instead of masking the K loads
    short8 qf = {};
    if (quad < 2)
        qf = *(const short8*)(Q + ((size_t)(qt * 16 + qrow)) * 64 + h * 16 + quad * 8);

    const f32x4 zero4 = {0.f, 0.f, 0.f, 0.f};
    int kbase = chunk * 1024;
    const unsigned short* krow = K + (size_t)(kbase + qrow) * 64 + h * 16 + quad * 8;
    // permuted V: lane(quad,d=qrow) needs keys {4q+0..3} and {16+4q+0..3} of each 32-key block
    const unsigned short* vrow = Vt + ((size_t)(h * 16 + qrow)) * Nk + kbase + quad * 4;

    float la = 0.0f, lb = 0.0f;
    f32x4 acc = zero4;

    // distance-2 prefetch (kf unmasked: quads 2,3 feed A[m][k>=16], killed by qf=0)
    short8 kf0p[2], kf1p[2];
    short4v vap[2], vbp[2];
    #pragma unroll
    for (int i = 0; i < 2; ++i) {
        kf0p[i] = *(const short8*)(krow + (size_t)(i * 32) * 64);
        kf1p[i] = *(const short8*)(krow + (size_t)(i * 32 + 16) * 64);
        vap[i] = *(const short4v*)(vrow + i * 32);
        vbp[i] = *(const short4v*)(vrow + i * 32 + 16);
    }

    #pragma unroll 2
    for (int it = 0; it < 32; ++it) {
        short8 kf0 = kf0p[it & 1], kf1 = kf1p[it & 1];
        short4v va = vap[it & 1], vb = vbp[it & 1];
        if (it < 30) {
            int off = (it + 2) * 32;
            kf0p[it & 1] = *(const short8*)(krow + (size_t)off * 64);
            kf1p[it & 1] = *(const short8*)(krow + (size_t)(off + 16) * 64);
            vap[it & 1] = *(const short4v*)(vrow + off);
            vbp[it & 1] = *(const short4v*)(vrow + off + 16);
        }

        f32x4 s0 = __builtin_amdgcn_mfma_f32_16x16x32_bf16(kf0, qf, zero4, 0, 0, 0);
        f32x4 s1 = __builtin_amdgcn_mfma_f32_16x16x32_bf16(kf1, qf, zero4, 0, 0, 0);

        float p00 = e2(s0.x - m), p01 = e2(s0.y - m);
        float p02 = e2(s0.z - m), p03 = e2(s0.w - m);
        float p10 = e2(s1.x - m), p11 = e2(s1.y - m);
        float p12 = e2(s1.z - m), p13 = e2(s1.w - m);
        la += (p00 + p01) + (p02 + p03);
        lb += (p10 + p11) + (p12 + p13);

        // P already in B-layout given the permuted V fragment
        short8 pf;
        ((unsigned int*)&pf)[0] = pk_bf16_tr(p00, p01);
        ((unsigned int*)&pf)[1] = pk_bf16_tr(p02, p03);
        ((unsigned int*)&pf)[2] = pk_bf16_tr(p10, p11);
        ((unsigned int*)&pf)[3] = pk_bf16_tr(p12, p13);
        short8 vf;
        *(short4v*)&vf = va;
        *((short4v*)&vf + 1) = vb;

        acc = __builtin_amdgcn_mfma_f32_16x16x32_bf16(vf, pf, acc, 0, 0, 0);
    }

    float l = la + lb;
    float ltot = l + __shfl_xor(l, 16, 64);
    ltot += __shfl_xor(ltot, 32, 64);

    float* pb = partial + (size_t)T * 288;
    *(f32x4*)&pb[qrow * 16 + quad * 4] = acc;
    if (quad == 0) { pb[256 + qrow] = m; pb[272 + qrow] = ltot; }
}

// ---------------- merge chunk partials + residual + layernorm (both dirs) ----------------
__global__ __launch_bounds__(256) void merge_ln_kernel(
    const float* __restrict__ partial,
    const float* __restrict__ h_m, const float* __restrict__ h_p,
    const float* __restrict__ gm, const float* __restrict__ bm,
    const float* __restrict__ gp, const float* __restrict__ bp_,
    float* __restrict__ out)
{
    int t = threadIdx.x;
    int grow = blockIdx.x * 4 + (t >> 6);
    int c = t & 63;
    const float *pbase, *hbuf, *g, *bb; float* o; int NC, row;
    if (grow < NM) { pbase = partial;               hbuf = h_m; g = gm; bb = bm;  o = out;             NC = 8; row = grow; }
    else           { pbase = partial + 4096 * 288;  hbuf = h_p; g = gp; bb = bp_; o = out + NM * 64;   NC = 2; row = grow - NM; }
    int hi = c >> 4, d = c & 15;
    int qt = row >> 4, ql = row & 15;
    const float* base = pbase + (size_t)(qt * 4 + hi) * NC * 288;
    float M = -3.0e38f;
    for (int cc = 0; cc < NC; ++cc) M = fmaxf(M, base[cc * 288 + 256 + ql]);
    float L = 0.0f, A = 0.0f;
    for (int cc = 0; cc < NC; ++cc) {
        float w = e2(base[cc * 288 + 256 + ql] - M);
        L += base[cc * 288 + 272 + ql] * w;
        A += base[cc * 288 + ql * 16 + d] * w;
    }
    float v = hbuf[(size_t)row * 64 + c] + A / L;
    float s = v;
    #pragma unroll
    for (int o2 = 32; o2 >= 1; o2 >>= 1) s += __shfl_xor(s, o2, 64);
    float mu = s * (1.0f / 64.0f);
    float dv = v - mu;
    float sq = dv * dv;
    #pragma unroll
    for (int o2 = 32; o2 >= 1; o2 >>= 1) sq += __shfl_xor(sq, o2, 64);
    float var = sq * (1.0f / 64.0f);
    o[(size_t)row * 64 + c] = dv * rsqrtf(var + 1e-5f) * g[c] + bb[c];
}

extern "C" void kernel_launch(void* const* d_in, const int* in_sizes, int n_in,
                              void* d_out, int out_size, void* d_ws, size_t ws_size,
                              hipStream_t stream)
{
    const float* x_mol   = (const float*)d_in[0];
    const int*   ei_mol  = (const int*)  d_in[1];
    const float* ea_mol  = (const float*)d_in[2];
    const float* x_prot  = (const float*)d_in[3];
    const int*   ei_prot = (const int*)  d_in[4];
    const float* ea_prot = (const float*)d_in[5];
    const float* mol_w1  = (const float*)d_in[6];
    const float* mol_b1  = (const float*)d_in[7];
    const float* mol_w2  = (const float*)d_in[8];
    const float* mol_b2  = (const float*)d_in[9];
    const float* prot_w1 = (const float*)d_in[10];
    const float* prot_b1 = (const float*)d_in[11];
    const float* prot_w2 = (const float*)d_in[12];
    const float* prot_b2 = (const float*)d_in[13];
    const float* mp_wq = (const float*)d_in[14]; const float* mp_bq = (const float*)d_in[15];
    const float* mp_wk = (const float*)d_in[16]; const float* mp_bk = (const float*)d_in[17];
    const float* mp_wv = (const float*)d_in[18]; const float* mp_bv = (const float*)d_in[19];
    const float* pm_wq = (const float*)d_in[20]; const float* pm_bq = (const float*)d_in[21];
    const float* pm_wk = (const float*)d_in[22]; const float* pm_bk = (const float*)d_in[23];
    const float* pm_wv = (const float*)d_in[24]; const float* pm_bv = (const float*)d_in[25];
    const float* ln_mol_g  = (const float*)d_in[26];
    const float* ln_mol_b  = (const float*)d_in[27];
    const float* ln_prot_g = (const float*)d_in[28];
    const float* ln_prot_b = (const float*)d_in[29];

    float* ws = (float*)d_ws;
    // float region
    float* h_mol   = ws;                         // 131072
    float* h_prot  = h_mol + 131072;             // 524288
    float* partial = h_prot + 524288;            // 8192*288 = 2359296 (mol rows 0..4095, prot 4096..8191)
    float* h0_mol  = partial;                    // alias: dead before attn writes
    float* h0_prot = h0_mol + 131072;
    // int region
    int* ip      = (int*)(partial + 2359296);
    int* cnt_m   = ip;                 // 2048
    int* cnt_p   = cnt_m + 2048;       // 8192
    int* norms   = cnt_p + 8192;       // 4  (0=Qm,1=Km,2=Qp,3=Kp; float bits)
    int* start_m = norms + 4;          // 2052 (2049 used)
    int* start_p = start_m + 2052;     // 8196 (8193 used)
    int* cur_m   = start_p + 8196;     // 2048
    int* cur_p   = cur_m + 2048;       // 8192
    int* pidx_m  = cur_p + 8192;       // 32768  packed (edge<<11)|src
    int* pidx_p  = pidx_m + 32768;     // 262144 packed (edge<<13)|src
    // bf16 region (16B-aligned by construction); K arrays must not be region-last
    // (attn reads up to 32 shorts past Km/Kp for h=3 unmasked loads)
    unsigned short* bf = (unsigned short*)(pidx_p + 262144);
    unsigned short* Qm  = bf;            // 131072
    unsigned short* Km  = Qm + 131072;   // 131072  (followed by Vtm: OOB-safe)
    unsigned short* Vtm = Km + 131072;   // 131072  [64][NM]
    unsigned short* Qp  = Vtm + 131072;  // 524288
    unsigned short* Kp  = Qp + 524288;   // 524288  (followed by Vtp: OOB-safe)
    unsigned short* Vtp = Kp + 524288;   // 524288  [64][NP]

    // zero counters + norms (contiguous)
    hipMemsetAsync(cnt_m, 0, (size_t)(2048 + 8192 + 4) * sizeof(int), stream);

    const int EB = (EM + EP) / 256;   // 1152
    hist_kernel<<<EB, 256, 0, stream>>>(ei_mol, ei_prot, cnt_m, cnt_p);
    scan_kernel<<<2, 256, 0, stream>>>(cnt_m, cnt_p, start_m, start_p, cur_m, cur_p);
    scatter_kernel<<<EB, 256, 0, stream>>>(ei_mol, ei_prot, cur_m, cur_p, pidx_m, pidx_p);
    node_aggr_kernel<<<(NM + NP) / 4, 256, 0, stream>>>(
        x_mol, ea_mol, start_m, pidx_m,
        x_prot, ea_prot, start_p, pidx_p, h0_mol, h0_prot);

    gine_mlp_kernel<<<(NM + NP) / 16, 256, 0, stream>>>(
        h0_mol, h0_prot, mol_w1, mol_b1, mol_w2, mol_b2,
        prot_w1, prot_b1, prot_w2, prot_b2, h_mol, h_prot);

    qkv_bf16_kernel<<<(NM + NP) / 16, 256, 0, stream>>>(
        h_mol, h_prot,
        mp_wq, mp_bq, pm_wk, pm_bk, pm_wv, pm_bv,
        pm_wq, pm_bq, mp_wk, mp_bk, mp_wv, mp_bv,
        Qm, Km, Vtm, Qp, Kp, Vtp, norms);

    // both attention directions in one dispatch: 2048 blocks x 4 waves = 8192 tasks
    attn_kernel<<<2048, 256, 0, stream>>>(Qm, Km, Vtm, Qp, Kp, Vtp, norms, partial);

    float* out = (float*)d_out;
    merge_ln_kernel<<<(NM + NP) / 4, 256, 0, stream>>>(
        partial, h_mol, h_prot, ln_mol_g, ln_mol_b, ln_prot_g, ln_prot_b, out);
}

// Round 8
// 305.294 us; speedup vs baseline: 1.2483x; 1.2483x over previous
//
#include <hip/hip_runtime.h>

#define NM 2048
#define EM 32768
#define NP 8192
#define EP 262144

typedef __attribute__((ext_vector_type(8))) short short8;
typedef __attribute__((ext_vector_type(4))) float f32x4;

#define LOG2E 1.44269504088896340736f

__device__ __forceinline__ float e2(float x) { return __builtin_amdgcn_exp2f(x); }
// pack two fp32 -> bf16x2 by TRUNCATION (1 inst); P in [0,1], validated r7 (absmax 0.031)
__device__ __forceinline__ unsigned int pk_bf16_tr(float a, float b) {
    return __builtin_amdgcn_perm(__float_as_uint(a), __float_as_uint(b), 0x03020706u);
}
__device__ __forceinline__ unsigned short cvt_bf16(float f) {
    unsigned int u = __float_as_uint(f);
    u = (u + 0x7fff + ((u >> 16) & 1)) >> 16;   // RNE
    return (unsigned short)u;
}

// ---------------- phase 1: histogram of dst (both graphs) ----------------
__global__ __launch_bounds__(256) void hist_kernel(
    const int* __restrict__ ei_m, const int* __restrict__ ei_p,
    int* __restrict__ cnt_m, int* __restrict__ cnt_p)
{
    int idx = blockIdx.x * 256 + threadIdx.x;
    if (idx < EM) atomicAdd(&cnt_m[ei_m[EM + idx]], 1);
    int j = idx - EM;
    if (j >= 0 && j < EP) atomicAdd(&cnt_p[ei_p[EP + j]], 1);
}

// ---------------- phase 2: exclusive prefix sum (block 0 = mol, block 1 = prot) ----------------
__global__ __launch_bounds__(256) void scan_kernel(
    const int* __restrict__ cnt_m, const int* __restrict__ cnt_p,
    int* __restrict__ start_m, int* __restrict__ start_p,
    int* __restrict__ cur_m, int* __restrict__ cur_p)
{
    const int* cnt; int* start; int* cur; int n;
    if (blockIdx.x == 0) { cnt = cnt_m; start = start_m; cur = cur_m; n = NM; }
    else                 { cnt = cnt_p; start = start_p; cur = cur_p; n = NP; }
    int per = n >> 8;
    int tid = threadIdx.x;
    int base = tid * per;
    int s = 0;
    for (int i = 0; i < per; i++) s += cnt[base + i];
    __shared__ int wsum[4];
    int lane = tid & 63, w = tid >> 6;
    int v = s;
    #pragma unroll
    for (int off = 1; off < 64; off <<= 1) {
        int u = __shfl_up(v, off, 64);
        if (lane >= off) v += u;
    }
    if (lane == 63) wsum[w] = v;
    __syncthreads();
    int wo = 0;
    for (int i = 0; i < w; i++) wo += wsum[i];
    int run = wo + v - s;   // exclusive prefix for this thread's range
    for (int i = 0; i < per; i++) {
        start[base + i] = run; cur[base + i] = run;
        run += cnt[base + i];
    }
    if (tid == 255) start[n] = run;
}

// ------- phase 3: scatter packed (edge<<sh)|src into dst-sorted order -------
__global__ __launch_bounds__(256) void scatter_kernel(
    const int* __restrict__ ei_m, const int* __restrict__ ei_p,
    int* __restrict__ cur_m, int* __restrict__ cur_p,
    int* __restrict__ pidx_m, int* __restrict__ pidx_p)
{
    int idx = blockIdx.x * 256 + threadIdx.x;
    if (idx < EM) {
        int d = ei_m[EM + idx];
        int pos = atomicAdd(&cur_m[d], 1);
        pidx_m[pos] = (idx << 11) | ei_m[idx];          // NM=2048 -> 11 src bits
    }
    int j = idx - EM;
    if (j >= 0 && j < EP) {
        int d = ei_p[EP + j];
        int pos = atomicAdd(&cur_p[d], 1);
        pidx_p[pos] = (j << 13) | ei_p[j];              // NP=8192 -> 13 src bits
    }
}

// ------- phase 4: atomic-free segmented reduce; h0 = x + mean(relu(x[src]+ea)) -------
__global__ __launch_bounds__(256) void node_aggr_kernel(
    const float* __restrict__ x_m, const float* __restrict__ ea_m,
    const int* __restrict__ start_m, const int* __restrict__ pidx_m,
    const float* __restrict__ x_p, const float* __restrict__ ea_p,
    const int* __restrict__ start_p, const int* __restrict__ pidx_p,
    float* __restrict__ h0_m, float* __restrict__ h0_p)
{
    int wave = threadIdx.x >> 6, lane = threadIdx.x & 63;
    int nid = blockIdx.x * 4 + wave;
    const float *x, *ea; const int *start, *pidx; float* h0; int n, sh, msk;
    if (nid < NM) { x = x_m; ea = ea_m; start = start_m; pidx = pidx_m; h0 = h0_m; n = nid; sh = 11; msk = 2047; }
    else          { x = x_p; ea = ea_p; start = start_p; pidx = pidx_p; h0 = h0_p; n = nid - NM; sh = 13; msk = 8191; }
    int b  = __builtin_amdgcn_readfirstlane(start[n]);
    int e  = __builtin_amdgcn_readfirstlane(start[n + 1]);
    int deg = e - b;
    const int* pp = pidx + b;
    float acc = 0.f;
    int j = 0;
    for (; j + 8 <= deg; j += 8) {
        int v0 = __builtin_amdgcn_readfirstlane(pp[j]);
        int v1 = __builtin_amdgcn_readfirstlane(pp[j + 1]);
        int v2 = __builtin_amdgcn_readfirstlane(pp[j + 2]);
        int v3 = __builtin_amdgcn_readfirstlane(pp[j + 3]);
        int v4 = __builtin_amdgcn_readfirstlane(pp[j + 4]);
        int v5 = __builtin_amdgcn_readfirstlane(pp[j + 5]);
        int v6 = __builtin_amdgcn_readfirstlane(pp[j + 6]);
        int v7 = __builtin_amdgcn_readfirstlane(pp[j + 7]);
        float a0 = ea[(size_t)(((unsigned)v0) >> sh) * 64 + lane];
        float a1 = ea[(size_t)(((unsigned)v1) >> sh) * 64 + lane];
        float a2 = ea[(size_t)(((unsigned)v2) >> sh) * 64 + lane];
        float a3 = ea[(size_t)(((unsigned)v3) >> sh) * 64 + lane];
        float a4 = ea[(size_t)(((unsigned)v4) >> sh) * 64 + lane];
        float a5 = ea[(size_t)(((unsigned)v5) >> sh) * 64 + lane];
        float a6 = ea[(size_t)(((unsigned)v6) >> sh) * 64 + lane];
        float a7 = ea[(size_t)(((unsigned)v7) >> sh) * 64 + lane];
        float y0 = x[(size_t)(v0 & msk) * 64 + lane];
        float y1 = x[(size_t)(v1 & msk) * 64 + lane];
        float y2 = x[(size_t)(v2 & msk) * 64 + lane];
        float y3 = x[(size_t)(v3 & msk) * 64 + lane];
        float y4 = x[(size_t)(v4 & msk) * 64 + lane];
        float y5 = x[(size_t)(v5 & msk) * 64 + lane];
        float y6 = x[(size_t)(v6 & msk) * 64 + lane];
        float y7 = x[(size_t)(v7 & msk) * 64 + lane];
        acc += fmaxf(y0 + a0, 0.f); acc += fmaxf(y1 + a1, 0.f);
        acc += fmaxf(y2 + a2, 0.f); acc += fmaxf(y3 + a3, 0.f);
        acc += fmaxf(y4 + a4, 0.f); acc += fmaxf(y5 + a5, 0.f);
        acc += fmaxf(y6 + a6, 0.f); acc += fmaxf(y7 + a7, 0.f);
    }
    for (; j < deg; ++j) {
        int v0 = __builtin_amdgcn_readfirstlane(pp[j]);
        acc += fmaxf(x[(size_t)(v0 & msk) * 64 + lane] + ea[(size_t)(((unsigned)v0) >> sh) * 64 + lane], 0.f);
    }
    float aggr = acc / fmaxf((float)deg, 1.f);
    h0[(size_t)n * 64 + lane] = x[(size_t)n * 64 + lane] + aggr;
}

// ---------------- GINE MLP (both graphs): h = relu( relu(h0@w1+b1)@w2 + b2 ) ----------------
__global__ __launch_bounds__(256) void gine_mlp_kernel(
    const float* __restrict__ h0_m, const float* __restrict__ h0_p,
    const float* __restrict__ w1m, const float* __restrict__ b1m,
    const float* __restrict__ w2m, const float* __restrict__ b2m,
    const float* __restrict__ w1p, const float* __restrict__ b1p,
    const float* __restrict__ w2p, const float* __restrict__ b2p,
    float* __restrict__ hm, float* __restrict__ hp)
{
    const float *h0, *w1, *b1, *w2, *b2; float* out; int row0;
    if (blockIdx.x < NM / 16) {
        h0 = h0_m; w1 = w1m; b1 = b1m; w2 = w2m; b2 = b2m; out = hm;
        row0 = blockIdx.x * 16;
    } else {
        h0 = h0_p; w1 = w1p; b1 = b1p; w2 = w2p; b2 = b2p; out = hp;
        row0 = (blockIdx.x - NM / 16) * 16;
    }
    __shared__ float sW1[4096], sW2[4096], sb1[64], sb2[64];
    __shared__ float sh0[16][64], sh1[16][64];
    int t = threadIdx.x;
    for (int i = t; i < 4096; i += 256) { sW1[i] = w1[i]; sW2[i] = w2[i]; }
    if (t < 64) { sb1[t] = b1[t]; sb2[t] = b2[t]; }
    for (int i = t; i < 16 * 64; i += 256) {
        int r = i >> 6, c = i & 63;
        sh0[r][c] = h0[(size_t)(row0 + r) * 64 + c];
    }
    __syncthreads();
    int j = t & 63, rs = t >> 6;
    for (int r = rs; r < 16; r += 4) {
        float a = sb1[j];
        #pragma unroll
        for (int c = 0; c < 64; c++) a += sh0[r][c] * sW1[c * 64 + j];
        sh1[r][j] = fmaxf(a, 0.0f);
    }
    __syncthreads();
    for (int r = rs; r < 16; r += 4) {
        float a = sb2[j];
        #pragma unroll
        for (int c = 0; c < 64; c++) a += sh1[r][c] * sW2[c * 64 + j];
        out[(size_t)(row0 + r) * 64 + j] = fmaxf(a, 0.0f);   // outer relu fused
    }
}

// -------- fused QKV -> bf16 (both sources) + per-direction Q/K max row-norms --------
__global__ __launch_bounds__(256) void qkv_bf16_kernel(
    const float* __restrict__ hm, const float* __restrict__ hp,
    const float* __restrict__ wq_m, const float* __restrict__ bq_m,
    const float* __restrict__ wk_m, const float* __restrict__ bk_m,
    const float* __restrict__ wv_m, const float* __restrict__ bv_m,
    const float* __restrict__ wq_p, const float* __restrict__ bq_p,
    const float* __restrict__ wk_p, const float* __restrict__ bk_p,
    const float* __restrict__ wv_p, const float* __restrict__ bv_p,
    unsigned short* __restrict__ Qm, unsigned short* __restrict__ Km, unsigned short* __restrict__ Vtm,
    unsigned short* __restrict__ Qp, unsigned short* __restrict__ Kp, unsigned short* __restrict__ Vtp,
    int* __restrict__ norms)
{
    const float *x, *wq, *bq, *wk, *bk, *wv, *bv;
    unsigned short *Q, *K, *Vt; int row0, N, nbase;
    if (blockIdx.x < NM / 16) {
        x = hm; wq = wq_m; bq = bq_m; wk = wk_m; bk = bk_m; wv = wv_m; bv = bv_m;
        Q = Qm; K = Km; Vt = Vtm; N = NM; row0 = blockIdx.x * 16; nbase = 0;
    } else {
        x = hp; wq = wq_p; bq = bq_p; wk = wk_p; bk = bk_p; wv = wv_p; bv = bv_p;
        Q = Qp; K = Kp; Vt = Vtp; N = NP; row0 = (blockIdx.x - NM / 16) * 16; nbase = 2;
    }
    __shared__ float sWq[4096], sWk[4096], sWv[4096];
    __shared__ float sbq[64], sbk[64], sbv[64];
    __shared__ float sh0[16][64];
    __shared__ float rmx[8];
    int t = threadIdx.x;
    for (int i = t; i < 4096; i += 256) { sWq[i] = wq[i]; sWk[i] = wk[i]; sWv[i] = wv[i]; }
    if (t < 64) { sbq[t] = bq[t]; sbk[t] = bk[t]; sbv[t] = bv[t]; }
    for (int i = t; i < 16 * 64; i += 256) {
        int r = i >> 6, c = i & 63;
        sh0[r][c] = x[(size_t)(row0 + r) * 64 + c];
    }
    __syncthreads();
    int j = t & 63, rs = t >> 6;
    float qmx = 0.f, kmx = 0.f;
    for (int r = rs; r < 16; r += 4) {
        float aq = sbq[j], ak = sbk[j], av = sbv[j];
        #pragma unroll
        for (int c = 0; c < 64; c++) {
            float h = sh0[r][c];
            aq += h * sWq[c * 64 + j];
            ak += h * sWk[c * 64 + j];
            av += h * sWv[c * 64 + j];
        }
        float qs = aq * (0.25f * LOG2E);      // fold 1/sqrt(HD) and log2(e)
        size_t o = (size_t)(row0 + r) * 64 + j;
        Q[o] = cvt_bf16(qs);
        K[o] = cvt_bf16(ak);
        Vt[(size_t)j * N + row0 + r] = cvt_bf16(av);
        float qsq = qs * qs, ksq = ak * ak;
        #pragma unroll
        for (int o2 = 1; o2 <= 8; o2 <<= 1) {
            qsq += __shfl_xor(qsq, o2, 64);
            ksq += __shfl_xor(ksq, o2, 64);
        }
        qmx = fmaxf(qmx, qsq);
        kmx = fmaxf(kmx, ksq);
    }
    qmx = fmaxf(qmx, __shfl_xor(qmx, 16, 64)); qmx = fmaxf(qmx, __shfl_xor(qmx, 32, 64));
    kmx = fmaxf(kmx, __shfl_xor(kmx, 16, 64)); kmx = fmaxf(kmx, __shfl_xor(kmx, 32, 64));
    if (j == 0) { rmx[rs] = qmx; rmx[4 + rs] = kmx; }
    __syncthreads();
    if (t == 0) {
        float q4 = fmaxf(fmaxf(rmx[0], rmx[1]), fmaxf(rmx[2], rmx[3]));
        float k4 = fmaxf(fmaxf(rmx[4], rmx[5]), fmaxf(rmx[6], rmx[7]));
        atomicMax(&norms[nbase],     __float_as_int(sqrtf(q4)));
        atomicMax(&norms[nbase + 1], __float_as_int(sqrtf(k4)));
    }
}

// ------- MFMA flash-attention: fixed C-S bound m, TWO q-tiles (32 queries) per wave -------
// r6-proven memory pattern (masked 16B K, 16B V, P via LDS) with K/V loads amortized 2x.
// 4096 waves: W<2048 mol->prot (NC=8), else prot->mol (NC=2); 1024 keys/chunk.
__global__ __launch_bounds__(256) void attn_kernel(
    const unsigned short* __restrict__ Qm, const unsigned short* __restrict__ Km,
    const unsigned short* __restrict__ Vtm,
    const unsigned short* __restrict__ Qp, const unsigned short* __restrict__ Kp,
    const unsigned short* __restrict__ Vtp,
    const int* __restrict__ norms, float* __restrict__ partial)
{
    __shared__ unsigned int plds[4][2][16][20];
    int t = threadIdx.x;
    int wave = t >> 6;
    int lane = t & 63;
    int qrow = lane & 15;
    int quad = lane >> 4;
    int W = blockIdx.x * 4 + wave;

    const unsigned short *Q, *K, *Vt; int Nk; float m;
    int chunk, h, qt2, Tbase, T1off;
    if (W < 2048) {
        Q = Qm; K = Kp; Vt = Vtp; Nk = NP;
        m = __int_as_float(norms[0]) * __int_as_float(norms[3]);
        chunk = W & 7; h = (W >> 3) & 3; qt2 = W >> 5;        // W = qt2*32 + h*8 + chunk
        Tbase = W + qt2 * 32; T1off = 32;                     // T(qt)=qt*32+h*8+chunk, qt=2*qt2
    } else {
        int W2 = W - 2048;
        Q = Qp; K = Km; Vt = Vtm; Nk = NM;
        m = __int_as_float(norms[2]) * __int_as_float(norms[1]);
        chunk = W2 & 1; h = (W2 >> 1) & 3; qt2 = W2 >> 3;     // W2 = qt2*8 + h*2 + chunk
        Tbase = 4096 + W2 + qt2 * 8; T1off = 8;
    }

    // B operands of QK for the two 16-query tiles (upper K half zeroed)
    short8 qfA = {}, qfB = {};
    if (quad < 2) {
        qfA = *(const short8*)(Q + ((size_t)(qt2 * 32 + qrow)) * 64 + h * 16 + quad * 8);
        qfB = *(const short8*)(Q + ((size_t)(qt2 * 32 + 16 + qrow)) * 64 + h * 16 + quad * 8);
    }

    const f32x4 zero4 = {0.f, 0.f, 0.f, 0.f};
    int kbase = chunk * 1024;
    const unsigned short* krow = K + (size_t)(kbase + qrow) * 64 + h * 16 + quad * 8;
    const unsigned short* vrow = Vt + ((size_t)(h * 16 + qrow)) * Nk + kbase + quad * 8;

    float lA = 0.0f, lB = 0.0f;
    f32x4 accA = zero4, accB = zero4;

    // distance-2 prefetch (r6 pattern)
    short8 kf0p[2], kf1p[2], vfp[2];
    #pragma unroll
    for (int i = 0; i < 2; ++i) {
        kf0p[i] = (short8){}; kf1p[i] = (short8){};
        if (quad < 2) {
            kf0p[i] = *(const short8*)(krow + (size_t)(i * 32) * 64);
            kf1p[i] = *(const short8*)(krow + (size_t)(i * 32 + 16) * 64);
        }
        vfp[i] = *(const short8*)(vrow + i * 32);
    }

    #pragma unroll 2
    for (int it = 0; it < 32; ++it) {
        short8 kf0 = kf0p[it & 1], kf1 = kf1p[it & 1], vf = vfp[it & 1];
        if (it < 30) {
            int off = (it + 2) * 32;
            if (quad < 2) {
                kf0p[it & 1] = *(const short8*)(krow + (size_t)off * 64);
                kf1p[it & 1] = *(const short8*)(krow + (size_t)(off + 16) * 64);
            }
            vfp[it & 1] = *(const short8*)(vrow + off);
        }

        f32x4 s0A = __builtin_amdgcn_mfma_f32_16x16x32_bf16(kf0, qfA, zero4, 0, 0, 0);
        f32x4 s1A = __builtin_amdgcn_mfma_f32_16x16x32_bf16(kf1, qfA, zero4, 0, 0, 0);
        f32x4 s0B = __builtin_amdgcn_mfma_f32_16x16x32_bf16(kf0, qfB, zero4, 0, 0, 0);
        f32x4 s1B = __builtin_amdgcn_mfma_f32_16x16x32_bf16(kf1, qfB, zero4, 0, 0, 0);

        float a00 = e2(s0A.x - m), a01 = e2(s0A.y - m), a02 = e2(s0A.z - m), a03 = e2(s0A.w - m);
        float a10 = e2(s1A.x - m), a11 = e2(s1A.y - m), a12 = e2(s1A.z - m), a13 = e2(s1A.w - m);
        float b00 = e2(s0B.x - m), b01 = e2(s0B.y - m), b02 = e2(s0B.z - m), b03 = e2(s0B.w - m);
        float b10 = e2(s1B.x - m), b11 = e2(s1B.y - m), b12 = e2(s1B.z - m), b13 = e2(s1B.w - m);
        lA += (((a00 + a01) + (a02 + a03)) + ((a10 + a11) + (a12 + a13)));
        lB += (((b00 + b01) + (b02 + b03)) + ((b10 + b11) + (b12 + b13)));

        uint2 wA0; wA0.x = pk_bf16_tr(a00, a01); wA0.y = pk_bf16_tr(a02, a03);
        uint2 wA1; wA1.x = pk_bf16_tr(a10, a11); wA1.y = pk_bf16_tr(a12, a13);
        uint2 wB0; wB0.x = pk_bf16_tr(b00, b01); wB0.y = pk_bf16_tr(b02, b03);
        uint2 wB1; wB1.x = pk_bf16_tr(b10, b11); wB1.y = pk_bf16_tr(b12, b13);
        *(uint2*)&plds[wave][0][qrow][quad * 2] = wA0;
        *(uint2*)&plds[wave][0][qrow][8 + quad * 2] = wA1;
        *(uint2*)&plds[wave][1][qrow][quad * 2] = wB0;
        *(uint2*)&plds[wave][1][qrow][8 + quad * 2] = wB1;
        short8 pfA = *(short8*)&plds[wave][0][qrow][quad * 4];   // B[k=quad*8+j][n=qrow]
        short8 pfB = *(short8*)&plds[wave][1][qrow][quad * 4];

        accA = __builtin_amdgcn_mfma_f32_16x16x32_bf16(vf, pfA, accA, 0, 0, 0);
        accB = __builtin_amdgcn_mfma_f32_16x16x32_bf16(vf, pfB, accB, 0, 0, 0);
    }

    float ltA = lA + __shfl_xor(lA, 16, 64); ltA += __shfl_xor(ltA, 32, 64);
    float ltB = lB + __shfl_xor(lB, 16, 64); ltB += __shfl_xor(ltB, 32, 64);

    float* pb0 = partial + (size_t)Tbase * 288;
    *(f32x4*)&pb0[qrow * 16 + quad * 4] = accA;
    if (quad == 0) pb0[272 + qrow] = ltA;
    float* pb1 = partial + (size_t)(Tbase + T1off) * 288;
    *(f32x4*)&pb1[qrow * 16 + quad * 4] = accB;
    if (quad == 0) pb1[272 + qrow] = ltB;
}

// ------- merge chunk partials + residual + layernorm (uniform m: plain sums) -------
__global__ __launch_bounds__(256) void merge_ln_kernel(
    const float* __restrict__ partial,
    const float* __restrict__ h_m, const float* __restrict__ h_p,
    const float* __restrict__ gm, const float* __restrict__ bm,
    const float* __restrict__ gp, const float* __restrict__ bp_,
    float* __restrict__ out)
{
    int t = threadIdx.x;
    int grow = blockIdx.x * 4 + (t >> 6);
    int c = t & 63;
    const float *pbase, *hbuf, *g, *bb; float* o; int NC, row;
    if (grow < NM) { pbase = partial;               hbuf = h_m; g = gm; bb = bm;  o = out;             NC = 8; row = grow; }
    else           { pbase = partial + 4096 * 288;  hbuf = h_p; g = gp; bb = bp_; o = out + NM * 64;   NC = 2; row = grow - NM; }
    int hi = c >> 4, d = c & 15;
    int qt = row >> 4, ql = row & 15;
    const float* base = pbase + (size_t)(qt * 4 + hi) * NC * 288;
    float L = 0.0f, A = 0.0f;
    for (int cc = 0; cc < NC; ++cc) {
        L += base[cc * 288 + 272 + ql];
        A += base[cc * 288 + ql * 16 + d];
    }
    float v = hbuf[(size_t)row * 64 + c] + A / L;
    float s = v;
    #pragma unroll
    for (int o2 = 32; o2 >= 1; o2 >>= 1) s += __shfl_xor(s, o2, 64);
    float mu = s * (1.0f / 64.0f);
    float dv = v - mu;
    float sq = dv * dv;
    #pragma unroll
    for (int o2 = 32; o2 >= 1; o2 >>= 1) sq += __shfl_xor(sq, o2, 64);
    float var = sq * (1.0f / 64.0f);
    o[(size_t)row * 64 + c] = dv * rsqrtf(var + 1e-5f) * g[c] + bb[c];
}

extern "C" void kernel_launch(void* const* d_in, const int* in_sizes, int n_in,
                              void* d_out, int out_size, void* d_ws, size_t ws_size,
                              hipStream_t stream)
{
    const float* x_mol   = (const float*)d_in[0];
    const int*   ei_mol  = (const int*)  d_in[1];
    const float* ea_mol  = (const float*)d_in[2];
    const float* x_prot  = (const float*)d_in[3];
    const int*   ei_prot = (const int*)  d_in[4];
    const float* ea_prot = (const float*)d_in[5];
    const float* mol_w1  = (const float*)d_in[6];
    const float* mol_b1  = (const float*)d_in[7];
    const float* mol_w2  = (const float*)d_in[8];
    const float* mol_b2  = (const float*)d_in[9];
    const float* prot_w1 = (const float*)d_in[10];
    const float* prot_b1 = (const float*)d_in[11];
    const float* prot_w2 = (const float*)d_in[12];
    const float* prot_b2 = (const float*)d_in[13];
    const float* mp_wq = (const float*)d_in[14]; const float* mp_bq = (const float*)d_in[15];
    const float* mp_wk = (const float*)d_in[16]; const float* mp_bk = (const float*)d_in[17];
    const float* mp_wv = (const float*)d_in[18]; const float* mp_bv = (const float*)d_in[19];
    const float* pm_wq = (const float*)d_in[20]; const float* pm_bq = (const float*)d_in[21];
    const float* pm_wk = (const float*)d_in[22]; const float* pm_bk = (const float*)d_in[23];
    const float* pm_wv = (const float*)d_in[24]; const float* pm_bv = (const float*)d_in[25];
    const float* ln_mol_g  = (const float*)d_in[26];
    const float* ln_mol_b  = (const float*)d_in[27];
    const float* ln_prot_g = (const float*)d_in[28];
    const float* ln_prot_b = (const float*)d_in[29];

    float* ws = (float*)d_ws;
    // float region
    float* h_mol   = ws;                         // 131072
    float* h_prot  = h_mol + 131072;             // 524288
    float* partial = h_prot + 524288;            // 8192*288 (mol tasks 0..4095, prot 4096..8191)
    float* h0_mol  = partial;                    // alias: dead before attn writes
    float* h0_prot = h0_mol + 131072;
    // int region
    int* ip      = (int*)(partial + 2359296);
    int* cnt_m   = ip;                 // 2048
    int* cnt_p   = cnt_m + 2048;       // 8192
    int* norms   = cnt_p + 8192;       // 4  (0=Qm,1=Km,2=Qp,3=Kp; float bits)
    int* start_m = norms + 4;          // 2052 (2049 used)
    int* start_p = start_m + 2052;     // 8196 (8193 used)
    int* cur_m   = start_p + 8196;     // 2048
    int* cur_p   = cur_m + 2048;       // 8192
    int* pidx_m  = cur_p + 8192;       // 32768
    int* pidx_p  = pidx_m + 32768;     // 262144
    // bf16 region; K arrays not region-last (prefetch may read 32 rows past chunk end)
    unsigned short* bf = (unsigned short*)(pidx_p + 262144);
    unsigned short* Qm  = bf;            // 131072
    unsigned short* Km  = Qm + 131072;   // 131072  (followed by Vtm: OOB-safe)
    unsigned short* Vtm = Km + 131072;   // 131072  [64][NM]
    unsigned short* Qp  = Vtm + 131072;  // 524288
    unsigned short* Kp  = Qp + 524288;   // 524288  (followed by Vtp: OOB-safe)
    unsigned short* Vtp = Kp + 524288;   // 524288  [64][NP]

    hipMemsetAsync(cnt_m, 0, (size_t)(2048 + 8192 + 4) * sizeof(int), stream);

    const int EB = (EM + EP) / 256;   // 1152
    hist_kernel<<<EB, 256, 0, stream>>>(ei_mol, ei_prot, cnt_m, cnt_p);
    scan_kernel<<<2, 256, 0, stream>>>(cnt_m, cnt_p, start_m, start_p, cur_m, cur_p);
    scatter_kernel<<<EB, 256, 0, stream>>>(ei_mol, ei_prot, cur_m, cur_p, pidx_m, pidx_p);
    node_aggr_kernel<<<(NM + NP) / 4, 256, 0, stream>>>(
        x_mol, ea_mol, start_m, pidx_m,
        x_prot, ea_prot, start_p, pidx_p, h0_mol, h0_prot);

    gine_mlp_kernel<<<(NM + NP) / 16, 256, 0, stream>>>(
        h0_mol, h0_prot, mol_w1, mol_b1, mol_w2, mol_b2,
        prot_w1, prot_b1, prot_w2, prot_b2, h_mol, h_prot);

    qkv_bf16_kernel<<<(NM + NP) / 16, 256, 0, stream>>>(
        h_mol, h_prot,
        mp_wq, mp_bq, pm_wk, pm_bk, pm_wv, pm_bv,
        pm_wq, pm_bq, mp_wk, mp_bk, mp_wv, mp_bv,
        Qm, Km, Vtm, Qp, Kp, Vtp, norms);

    // both directions, 32 queries/wave: 1024 blocks x 4 waves = 4096 tasks
    attn_kernel<<<1024, 256, 0, stream>>>(Qm, Km, Vtm, Qp, Kp, Vtp, norms, partial);

    float* out = (float*)d_out;
    merge_ln_kernel<<<(NM + NP) / 4, 256, 0, stream>>>(
        partial, h_mol, h_prot, ln_mol_g, ln_mol_b, ln_prot_g, ln_prot_b, out);
}